// Round 2
// baseline (570.765 us; speedup 1.0000x reference)
//
#include <hip/hip_runtime.h>

#define NGRAPH 64
#define NN 128
#define DI 64
#define DO 64

typedef __attribute__((ext_vector_type(8))) short short8;
typedef __attribute__((ext_vector_type(4))) short short4v;
typedef __attribute__((ext_vector_type(4))) float f32x4;

// ---------------- workspace layout ----------------
// AT    : short [NGRAPH][NN][NN]  @ 0              (2 MB)   AT[b][j][k] = bf16(A[b][k][j]) (exact, 0/1)
// colsum: float [NGRAPH][NN]      @ 2MB            (32 KB)  colsum[b][j] = sum_k A[b][k][j]
// WThi  : short [DO][DI]          @ 2MB+32K        (8 KB)   bf16 hi plane of W^T
// WTlo  : short [DO][DI]          @ 2MB+40K        (8 KB)   bf16 lo plane of W^T
#define OFF_COLSUM (2u * 1024u * 1024u)
#define OFF_WTHI   (OFF_COLSUM + 32u * 1024u)
#define OFF_WTLO   (OFF_WTHI + 8u * 1024u)
#define WS_NEED    (OFF_WTLO + 8u * 1024u)

__device__ __forceinline__ unsigned short f2bf_rn(float f) {
    unsigned int u = __float_as_uint(f);
    u += 0x7FFFu + ((u >> 16) & 1u);          // round-to-nearest-even
    return (unsigned short)(u >> 16);
}
__device__ __forceinline__ float bf2f(unsigned short h) {
    return __uint_as_float(((unsigned int)h) << 16);
}

// ---------------- prep: A^T bf16 + colsum ----------------
__global__ __launch_bounds__(256) void prep_adj(const float* __restrict__ A,
                                                short* __restrict__ AT,
                                                float* __restrict__ colsum) {
    __shared__ float csp[2][NN];
    const int b  = blockIdx.x;
    const int j  = threadIdx.x & 127;
    const int kh = threadIdx.x >> 7;          // k-half 0/1
    const float* Ab = A + (size_t)b * NN * NN;
    short* ATr = AT + (size_t)b * NN * NN + (size_t)j * NN + kh * 64;
    float s = 0.f;
    for (int kc = 0; kc < 8; ++kc) {          // 8 chunks of 8 k
        short8 pk;
        #pragma unroll
        for (int u = 0; u < 8; ++u) {
            float a = Ab[(size_t)(kh * 64 + kc * 8 + u) * NN + j];  // coalesced over j
            s += a;
            pk[u] = (short)f2bf_rn(a);        // exact for 0/1
        }
        *(short8*)(ATr + kc * 8) = pk;        // 16B store, contiguous k
    }
    csp[kh][j] = s;
    __syncthreads();
    if (kh == 0) colsum[b * NN + j] = csp[0][j] + csp[1][j];
}

// ---------------- prep: W^T bf16 2-split ----------------
__global__ void prep_w(const float* __restrict__ W,
                       short* __restrict__ WThi, short* __restrict__ WTlo) {
    const int t = threadIdx.x;                // 256 threads
    for (int m = 0; m < 16; ++m) {
        int idx = m * 256 + t;                // idx = e*64 + d
        int e = idx >> 6, d = idx & 63;
        float x = W[d * 64 + e];
        unsigned short h = f2bf_rn(x);
        unsigned short lo = f2bf_rn(x - bf2f(h));
        WThi[idx] = (short)h;
        WTlo[idx] = (short)lo;
    }
}

// ---------------- main fused kernel ----------------
// One block per (b,i); 256 threads = 4 waves.
// Phase 1 (MFMA): tX[k][e] = X[b,i,k,:]·W  via X 2-split × W 2-split (3 terms),
//                 written to LDS transposed as bf16 hi/lo planes tXT[e][k].
// Phase 2 (MFMA): O^T[e][j] = sum_k tXT[e,k]·AT[j,k]  (adjacency exact bf16),
//                 epilogue adds bias[e]*colsum[j], stores float4.
#define TSTR 136   // tXT row stride (shorts): rows 16B-aligned (272 = 17*16)

__global__ __launch_bounds__(256, 3)
void ngnn_main(const float* __restrict__ X,
               const short* __restrict__ AT,
               const float* __restrict__ bias,
               const float* __restrict__ colsum,
               const short* __restrict__ WThi,
               const short* __restrict__ WTlo,
               float* __restrict__ out) {
    __shared__ short tXThi[DO][TSTR];
    __shared__ short tXTlo[DO][TSTR];

    const int tid = threadIdx.x;
    const int w   = tid >> 6;       // wave 0..3
    const int l   = tid & 63;
    const int lm  = l & 15;         // frag row/col
    const int lg  = l >> 4;         // k-group 0..3
    const int b   = blockIdx.x >> 7;

    const float* Xb = X + (size_t)blockIdx.x * (NN * DI);

    // --- W^T B-frags: lane holds WT[e = nt*16+lm][d = ks*32 + lg*8 .. +8] ---
    short8 wfh[4][2], wfl[4][2];
    #pragma unroll
    for (int nt = 0; nt < 4; ++nt)
        #pragma unroll
        for (int ks = 0; ks < 2; ++ks) {
            int off = (nt * 16 + lm) * DI + ks * 32 + lg * 8;
            wfh[nt][ks] = *(const short8*)(WThi + off);
            wfl[nt][ks] = *(const short8*)(WTlo + off);
        }

    // --- phase 1: two 16-row k-tiles per wave ---
    #pragma unroll
    for (int mt = 0; mt < 2; ++mt) {
        const int krow = (w * 2 + mt) * 16 + lm;          // tuple index k (M dim)
        const float* xr = Xb + (size_t)krow * DI;
        short8 xh[2], xl[2];
        #pragma unroll
        for (int ks = 0; ks < 2; ++ks) {
            float4 a = ((const float4*)xr)[ks * 8 + lg * 2];
            float4 c4 = ((const float4*)xr)[ks * 8 + lg * 2 + 1];
            float v[8] = {a.x, a.y, a.z, a.w, c4.x, c4.y, c4.z, c4.w};
            #pragma unroll
            for (int u = 0; u < 8; ++u) {
                unsigned short h = f2bf_rn(v[u]);
                xh[ks][u] = (short)h;
                xl[ks][u] = (short)f2bf_rn(v[u] - bf2f(h));
            }
        }
        #pragma unroll
        for (int nt = 0; nt < 4; ++nt) {
            f32x4 c = {0.f, 0.f, 0.f, 0.f};
            #pragma unroll
            for (int ks = 0; ks < 2; ++ks) {
                c = __builtin_amdgcn_mfma_f32_16x16x32_bf16(xh[ks], wfh[nt][ks], c, 0, 0, 0);
                c = __builtin_amdgcn_mfma_f32_16x16x32_bf16(xh[ks], wfl[nt][ks], c, 0, 0, 0);
                c = __builtin_amdgcn_mfma_f32_16x16x32_bf16(xl[ks], wfh[nt][ks], c, 0, 0, 0);
            }
            // C/D: row(k) = (lg*4 + r) + tile base, col(e) = lm + nt*16
            const int e  = nt * 16 + lm;
            const int kb = (w * 2 + mt) * 16 + lg * 4;
            short4v h4, l4;
            #pragma unroll
            for (int r = 0; r < 4; ++r) {
                unsigned short h = f2bf_rn(c[r]);
                h4[r] = (short)h;
                l4[r] = (short)f2bf_rn(c[r] - bf2f(h));
            }
            *(short4v*)&tXThi[e][kb] = h4;   // 8B store, 8B-aligned (kb%4==0)
            *(short4v*)&tXTlo[e][kb] = l4;
        }
    }
    __syncthreads();

    // --- phase 2: wave w owns e-tile w; 8 j-tiles; K = 128 over 4 slices ---
    const short* ATb = AT + (size_t)b * NN * NN;
    f32x4 acc[8];
    #pragma unroll
    for (int nt = 0; nt < 8; ++nt) acc[nt] = (f32x4){0.f, 0.f, 0.f, 0.f};

    #pragma unroll
    for (int ks = 0; ks < 4; ++ks) {
        short8 ah = *(const short8*)&tXThi[w * 16 + lm][ks * 32 + lg * 8];
        short8 al = *(const short8*)&tXTlo[w * 16 + lm][ks * 32 + lg * 8];
        #pragma unroll
        for (int nt = 0; nt < 8; ++nt) {
            short8 bf = *(const short8*)(ATb + (size_t)(nt * 16 + lm) * NN + ks * 32 + lg * 8);
            acc[nt] = __builtin_amdgcn_mfma_f32_16x16x32_bf16(ah, bf, acc[nt], 0, 0, 0);
            acc[nt] = __builtin_amdgcn_mfma_f32_16x16x32_bf16(al, bf, acc[nt], 0, 0, 0);
        }
    }

    // --- epilogue: out[b,i,j,e] = O^T[e][j] + bias[e]*colsum[b,j] ---
    const int e0 = w * 16 + lg * 4;
    const float4 bv = *(const float4*)(bias + e0);
    float* outb = out + (size_t)blockIdx.x * (NN * DO);
    #pragma unroll
    for (int nt = 0; nt < 8; ++nt) {
        const int j = nt * 16 + lm;
        const float cs = colsum[b * NN + j];
        float4 o;
        o.x = acc[nt][0] + bv.x * cs;
        o.y = acc[nt][1] + bv.y * cs;
        o.z = acc[nt][2] + bv.z * cs;
        o.w = acc[nt][3] + bv.w * cs;
        *(float4*)(outb + (size_t)j * DO + e0) = o;   // 16B store
    }
}

// ---------------- dense VALU fallback (zero workspace) ----------------
__global__ __launch_bounds__(256, 3)
void fallback_dense(const float* __restrict__ X,
                    const float* __restrict__ A,
                    const float* __restrict__ W,
                    const float* __restrict__ bias,
                    float* __restrict__ out) {
    __shared__ float tXs[NN][DO + 4];
    __shared__ float Ws[DI][DO];
    __shared__ float bs[DO];
    const int tid = threadIdx.x;
    const int bb = blockIdx.x >> 7;

    {
        const float4* Wv = (const float4*)W;
        float4* Wsv = (float4*)&Ws[0][0];
        #pragma unroll
        for (int t = 0; t < 4; ++t) Wsv[tid + 256 * t] = Wv[tid + 256 * t];
        if (tid < DO) bs[tid] = bias[tid];
    }
    __syncthreads();
    {
        const int k = tid & 127;
        const int e0 = (tid >> 7) * 32;
        const float4* Xv = (const float4*)(X + (size_t)blockIdx.x * (NN * DI) + (size_t)k * DI);
        float acc[32];
        #pragma unroll
        for (int q = 0; q < 32; ++q) acc[q] = 0.f;
        for (int dq = 0; dq < DI / 4; ++dq) {
            float4 xv = Xv[dq];
            const float xs[4] = {xv.x, xv.y, xv.z, xv.w};
            #pragma unroll
            for (int s = 0; s < 4; ++s) {
                const float4* wrow = (const float4*)&Ws[dq * 4 + s][e0];
                #pragma unroll
                for (int q = 0; q < 8; ++q) {
                    float4 wv = wrow[q];
                    acc[q * 4 + 0] = fmaf(xs[s], wv.x, acc[q * 4 + 0]);
                    acc[q * 4 + 1] = fmaf(xs[s], wv.y, acc[q * 4 + 1]);
                    acc[q * 4 + 2] = fmaf(xs[s], wv.z, acc[q * 4 + 2]);
                    acc[q * 4 + 3] = fmaf(xs[s], wv.w, acc[q * 4 + 3]);
                }
            }
        }
        float4* trow = (float4*)&tXs[k][e0];
        #pragma unroll
        for (int q = 0; q < 8; ++q)
            trow[q] = make_float4(acc[q * 4], acc[q * 4 + 1], acc[q * 4 + 2], acc[q * 4 + 3]);
    }
    __syncthreads();
    {
        const int lane = tid & 63;
        const int g = tid >> 6;
        const float bl = bs[lane];
        float* outb = out + (size_t)blockIdx.x * (NN * DO);
        for (int jj = 0; jj < 32; ++jj) {
            const int j = g * 32 + jj;
            const float* Acol = A + (size_t)bb * NN * NN + j;
            float acc2 = 0.f, cs = 0.f;
            for (int k = 0; k < NN; ++k) {
                float a = Acol[(size_t)k * NN];
                cs += a;
                acc2 = fmaf(a, tXs[k][lane], acc2);
            }
            outb[(size_t)j * DO + lane] = acc2 + bl * cs;
        }
    }
}

extern "C" void kernel_launch(void* const* d_in, const int* in_sizes, int n_in,
                              void* d_out, int out_size, void* d_ws, size_t ws_size,
                              hipStream_t stream) {
    const float* X    = (const float*)d_in[0];
    const float* A    = (const float*)d_in[1];
    const float* W    = (const float*)d_in[2];
    const float* bias = (const float*)d_in[3];
    float* out = (float*)d_out;

    if (d_ws != nullptr && ws_size >= WS_NEED) {
        char* ws = (char*)d_ws;
        short* ATp    = (short*)ws;
        float* colsum = (float*)(ws + OFF_COLSUM);
        short* WThi   = (short*)(ws + OFF_WTHI);
        short* WTlo   = (short*)(ws + OFF_WTLO);

        hipLaunchKernelGGL(prep_adj, dim3(NGRAPH), dim3(256), 0, stream, A, ATp, colsum);
        hipLaunchKernelGGL(prep_w, dim3(1), dim3(256), 0, stream, W, WThi, WTlo);
        hipLaunchKernelGGL(ngnn_main, dim3(NGRAPH * NN), dim3(256), 0, stream,
                           X, ATp, bias, colsum, WThi, WTlo, out);
    } else {
        hipLaunchKernelGGL(fallback_dense, dim3(NGRAPH * NN), dim3(256), 0, stream,
                           X, A, W, bias, out);
    }
}